// Round 10
// baseline (90.194 us; speedup 1.0000x reference)
//
#include <hip/hip_runtime.h>
#include <math.h>

// Problem constants
#define B_   4
#define DM   64   // d_model
#define DS   16   // d_state
#define HW_  1024 // 32*32
#define NV   9    // (2*1+1)^2 shifts

typedef float f32x4 __attribute__((ext_vector_type(4)));

// d_out layout: y_out (B,9,64,32,32) = 2359296 floats, then s_next (B,9,64,16,32,32)
#define Y_SIZE   2359296
// ws layout (floats): delta[B][64][1024], B_val[B][16][1024], C_val[B][16][1024]
#define WS_DELTA 0
#define WS_BV    (B_*DM*HW_)            // 262144
#define WS_CV    (WS_BV + B_*DS*HW_)    // 327680

// ---------------------------------------------------------------------------
// Kernel 1 (v4): three circular 3x3 convs. 4 output channels/thread,
// 8-ci LDS chunks, grid B*24*4 = 384 blocks, 256 threads. Unchanged (~8 us).
// ---------------------------------------------------------------------------
__global__ __launch_bounds__(256) void conv_kernel(
    const float* __restrict__ u,
    const float* __restrict__ Wd,
    const float* __restrict__ bd,
    const float* __restrict__ Wb,
    const float* __restrict__ Wc,
    const float* __restrict__ dtp,
    float* __restrict__ ws)
{
    __shared__ float su[8 * 320];      // 8 ci x 10 rows x 32 cols
    __shared__ float sw[DM * 9 * 4];   // [ci][tap][j], j = 4 output channels

    const int bid = blockIdx.x;
    const int b   = bid / 96;
    const int r   = bid % 96;
    const int g   = r >> 2;            // 0..23 channel-group (of 4)
    const int h0  = (r & 3) * 8;       // row-quarter base
    const int co0 = g * 4;

    const float* Wsrc;
    int cbase, mode;
    if (co0 < 64)      { Wsrc = Wd; cbase = co0;      mode = 0; }
    else if (co0 < 80) { Wsrc = Wb; cbase = co0 - 64; mode = 1; }
    else               { Wsrc = Wc; cbase = co0 - 80; mode = 2; }

    const int tid = threadIdx.x;

    for (int i = tid; i < DM * 9 * 4; i += 256) {
        const int j  = i & 3;
        const int ct = i >> 2;          // ci*9 + tap
        sw[i] = Wsrc[(cbase + j) * 576 + ct];
    }

    const int hl = tid >> 5;            // 0..7 local row
    const int w  = tid & 31;
    const int pix = ((h0 + hl) << 5) | w;

    float acc[4];
    #pragma unroll
    for (int j = 0; j < 4; ++j) acc[j] = 0.f;
    const float* ub = u + (size_t)b * DM * HW_;

    for (int c0 = 0; c0 < DM; c0 += 8) {
        __syncthreads();
        #pragma unroll
        for (int k = 0; k < 10; ++k) {
            const int i   = k * 256 + tid;
            const int cl  = i / 320;
            const int pos = i - cl * 320;
            const int rr  = pos >> 5;
            su[i] = ub[(c0 + cl) * HW_ + ((((h0 - 1 + rr) & 31) << 5) | (pos & 31))];
        }
        __syncthreads();
        #pragma unroll
        for (int cl = 0; cl < 8; ++cl) {
            #pragma unroll
            for (int kh = 0; kh < 3; ++kh) {
                const int rs = hl + kh;
                #pragma unroll
                for (int kw = 0; kw < 3; ++kw) {
                    const int ww = (w + kw + 31) & 31;
                    const float v = su[cl * 320 + ((rs << 5) | ww)];
                    const float4 w0 = *(const float4*)&sw[((c0 + cl) * 9 + kh * 3 + kw) * 4];
                    acc[0] = fmaf(v, w0.x, acc[0]);
                    acc[1] = fmaf(v, w0.y, acc[1]);
                    acc[2] = fmaf(v, w0.z, acc[2]);
                    acc[3] = fmaf(v, w0.w, acc[3]);
                }
            }
        }
    }

    if (mode == 0) {
        const float dt = dtp[0];
        #pragma unroll
        for (int j = 0; j < 4; ++j) {
            const float x  = acc[j] + bd[cbase + j] + dt;
            const float sp = fmaxf(x, 0.f) + log1pf(expf(-fabsf(x)));
            ws[WS_DELTA + ((size_t)b * DM + cbase + j) * HW_ + pix] = sp;
        }
    } else if (mode == 1) {
        #pragma unroll
        for (int j = 0; j < 4; ++j)
            ws[WS_BV + ((size_t)b * DS + cbase + j) * HW_ + pix] = acc[j];
    } else {
        #pragma unroll
        for (int j = 0; j < 4; ++j)
            ws[WS_CV + ((size_t)b * DS + cbase + j) * HW_ + pix] = acc[j];
    }
}

// ---------------------------------------------------------------------------
// Kernel 2 (v9): EXACT R6 v5 structure (best known: scan ~65 us), with ONE
// change: nontemporal stores removed (plain cached stores for s_next and y).
// A/B isolates the NT-store effect: the 7.2 TB/s fill kernels use cached
// stores, and NT buys no WRITE_SIZE reduction here, so NT may be throttling
// the write stream by bypassing L2 write-coalescing.
// 512 threads = 128 pixel-quads x 4 n-threads; grid B*NV*DM*2 = 4608 blocks.
// ---------------------------------------------------------------------------
__global__ __launch_bounds__(512) void scan_kernel(
    const float* __restrict__ u,
    const float* __restrict__ s_prev,
    const float* __restrict__ logA,
    const float* __restrict__ Dv,
    const float* __restrict__ ws,
    float* __restrict__ out)
{
    const int bid  = blockIdx.x >> 1;   // (b*9+v)*64 + c
    const int half = blockIdx.x & 1;
    const int c   = bid & 63;
    const int bv  = bid >> 6;
    const int v   = bv % 9;
    const int b   = bv / 9;

    __shared__ float sAr[DS], sIr[DS];
    __shared__ float syl[4 * 512];      // [nthr][quad*4+j]

    const int tid = threadIdx.x;
    if (tid < DS) {
        const float A = -__expf(logA[(c << 4) + tid]);
        sAr[tid] = A;
        sIr[tid] = 1.0f / A;
    }
    __syncthreads();

    const int quad = tid & 127;
    const int nthr = tid >> 7;          // 0..3, wave-uniform
    const int lane = tid & 63;
    const int nb   = nthr << 2;

    const int hw4 = (half << 9) | (quad << 2);   // first of 4 pixels
    const int h   = hw4 >> 5;

    const int sx  = v / 3 - 1;          // SHIFTS order: x outer, y inner
    const int syy = v % 3 - 1;
    const int hs  = (h + syy) & 31;
    const int rowbase = (hs << 5) | ((quad & 7) << 2);

    const int srcp = (lane & ~7) | ((lane + 1) & 7);  // next lane in row
    const int srcm = (lane & ~7) | ((lane + 7) & 7);  // prev lane in row

    const int bc = (b << 6) | c;

    const float* __restrict__ sp  = s_prev + ((size_t)bid << 14);
    float* __restrict__ so        = out + Y_SIZE + ((size_t)bid << 14);
    const float* __restrict__ bvp = ws + WS_BV + ((b << 14) | hw4);
    const float* __restrict__ cvp = ws + WS_CV + ((b << 14) | hw4);

    // s_prev first (HBM latency), then L2-resident operands
    float4 spv[4], bvv[4], cvv[4];
    #pragma unroll
    for (int i = 0; i < 4; ++i)
        spv[i] = *(const float4*)&sp[((nb + i) << 10) + rowbase];
    #pragma unroll
    for (int i = 0; i < 4; ++i) {
        bvv[i] = *(const float4*)&bvp[(nb + i) << 10];
        cvv[i] = *(const float4*)&cvp[(nb + i) << 10];
    }
    const float4 u4 = *(const float4*)&u[(bc << 10) | hw4];
    const float4 d4 = *(const float4*)&ws[WS_DELTA + ((bc << 10) | hw4)];

    float4 acc = make_float4(0.f, 0.f, 0.f, 0.f);
    #pragma unroll
    for (int i = 0; i < 4; ++i) {
        const int n = nb + i;
        float4 sh;
        if (sx > 0) {
            const float edge = __shfl(spv[i].x, srcp);
            sh = make_float4(spv[i].y, spv[i].z, spv[i].w, edge);
        } else if (sx < 0) {
            const float edge = __shfl(spv[i].w, srcm);
            sh = make_float4(edge, spv[i].x, spv[i].y, spv[i].z);
        } else {
            sh = spv[i];
        }
        const float A  = sAr[n];
        const float iA = sIr[n];
        float4 e;
        f32x4 s;
        e.x = __expf(d4.x * A);
        e.y = __expf(d4.y * A);
        e.z = __expf(d4.z * A);
        e.w = __expf(d4.w * A);
        s.x = fmaf(e.x, sh.x, (e.x - 1.f) * iA * bvv[i].x * u4.x);
        s.y = fmaf(e.y, sh.y, (e.y - 1.f) * iA * bvv[i].y * u4.y);
        s.z = fmaf(e.z, sh.z, (e.z - 1.f) * iA * bvv[i].z * u4.z);
        s.w = fmaf(e.w, sh.w, (e.w - 1.f) * iA * bvv[i].w * u4.w);
        *(f32x4*)&so[(n << 10) + hw4] = s;            // cached store (A/B vs NT)
        acc.x = fmaf(s.x, cvv[i].x, acc.x);
        acc.y = fmaf(s.y, cvv[i].y, acc.y);
        acc.z = fmaf(s.z, cvv[i].z, acc.z);
        acc.w = fmaf(s.w, cvv[i].w, acc.w);
    }

    // reduce y over the 4 n-threads
    *(float4*)&syl[(nthr << 9) | (quad << 2)] = make_float4(acc.x, acc.y, acc.z, acc.w);
    __syncthreads();
    if (tid < 128) {
        const float4 a0 = *(const float4*)&syl[(0 << 9) | (tid << 2)];
        const float4 a1 = *(const float4*)&syl[(1 << 9) | (tid << 2)];
        const float4 a2 = *(const float4*)&syl[(2 << 9) | (tid << 2)];
        const float4 a3 = *(const float4*)&syl[(3 << 9) | (tid << 2)];
        const float Dc = Dv[c];
        f32x4 y;
        y.x = a0.x + a1.x + a2.x + a3.x + u4.x * Dc;
        y.y = a0.y + a1.y + a2.y + a3.y + u4.y * Dc;
        y.z = a0.z + a1.z + a2.z + a3.z + u4.z * Dc;
        y.w = a0.w + a1.w + a2.w + a3.w + u4.w * Dc;
        *(f32x4*)&out[(bid << 10) | hw4] = y;         // cached store (A/B vs NT)
    }
}

extern "C" void kernel_launch(void* const* d_in, const int* in_sizes, int n_in,
                              void* d_out, int out_size, void* d_ws, size_t ws_size,
                              hipStream_t stream) {
    const float* u      = (const float*)d_in[0];
    const float* s_prev = (const float*)d_in[1];
    const float* Wd     = (const float*)d_in[2];
    const float* bd     = (const float*)d_in[3];
    const float* Wb     = (const float*)d_in[4];
    const float* Wc     = (const float*)d_in[5];
    const float* logA   = (const float*)d_in[6];
    const float* Dv     = (const float*)d_in[7];
    const float* dtp    = (const float*)d_in[8];
    float* out = (float*)d_out;
    float* ws  = (float*)d_ws;

    conv_kernel<<<B_ * 24 * 4, 256, 0, stream>>>(u, Wd, bd, Wb, Wc, dtp, ws);
    scan_kernel<<<B_ * NV * DM * 2, 512, 0, stream>>>(u, s_prev, logA, Dv, ws, out);
}

// Round 11
// 73.462 us; speedup vs baseline: 1.2278x; 1.2278x over previous
//
#include <hip/hip_runtime.h>
#include <math.h>

// Problem constants
#define B_   4
#define DM   64   // d_model
#define DS   16   // d_state
#define HW_  1024 // 32*32
#define NV   9    // (2*1+1)^2 shifts

typedef float f32x4 __attribute__((ext_vector_type(4)));

// d_out layout: y_out (B,9,64,32,32) = 2359296 floats, then s_next (B,9,64,16,32,32)
#define Y_SIZE   2359296
// ws layout (floats): delta[B][64][1024], B_val[B][16][1024], C_val[B][16][1024]
#define WS_DELTA 0
#define WS_BV    (B_*DM*HW_)            // 262144
#define WS_CV    (WS_BV + B_*DS*HW_)    // 327680

// ---------------------------------------------------------------------------
// Kernel 1 (v3, R5/R6 build): three circular 3x3 convs.
// 8 output channels per thread, 8-ci LDS chunks. Grid B*12*4 = 192 blocks.
// ---------------------------------------------------------------------------
__global__ __launch_bounds__(256) void conv_kernel(
    const float* __restrict__ u,
    const float* __restrict__ Wd,
    const float* __restrict__ bd,
    const float* __restrict__ Wb,
    const float* __restrict__ Wc,
    const float* __restrict__ dtp,
    float* __restrict__ ws)
{
    __shared__ float su[8 * 320];      // 8 ci x 10 rows x 32 cols
    __shared__ float sw[DM * 9 * 8];   // [ci][tap][j], j = 8 output channels

    const int bid = blockIdx.x;
    const int b   = bid / 48;
    const int r   = bid % 48;
    const int g   = r >> 2;            // 0..11 channel-group (of 8)
    const int h0  = (r & 3) * 8;       // row-quarter base
    const int co0 = g * 8;

    const float* Wsrc;
    int cbase, mode;
    if (co0 < 64)      { Wsrc = Wd; cbase = co0;      mode = 0; }
    else if (co0 < 80) { Wsrc = Wb; cbase = co0 - 64; mode = 1; }
    else               { Wsrc = Wc; cbase = co0 - 80; mode = 2; }

    const int tid = threadIdx.x;

    for (int i = tid; i < DM * 9 * 8; i += 256) {
        const int j  = i & 7;
        const int ct = i >> 3;          // ci*9 + tap
        sw[i] = Wsrc[(cbase + j) * 576 + ct];
    }

    const int hl = tid >> 5;            // 0..7 local row
    const int w  = tid & 31;
    const int pix = ((h0 + hl) << 5) | w;

    float acc[8];
    #pragma unroll
    for (int j = 0; j < 8; ++j) acc[j] = 0.f;
    const float* ub = u + (size_t)b * DM * HW_;

    for (int c0 = 0; c0 < DM; c0 += 8) {
        __syncthreads();
        #pragma unroll
        for (int k = 0; k < 10; ++k) {
            const int i   = k * 256 + tid;
            const int cl  = i / 320;
            const int pos = i - cl * 320;
            const int rr  = pos >> 5;
            su[i] = ub[(c0 + cl) * HW_ + ((((h0 - 1 + rr) & 31) << 5) | (pos & 31))];
        }
        __syncthreads();
        #pragma unroll
        for (int cl = 0; cl < 8; ++cl) {
            #pragma unroll
            for (int kh = 0; kh < 3; ++kh) {
                const int rs = hl + kh;
                #pragma unroll
                for (int kw = 0; kw < 3; ++kw) {
                    const int ww = (w + kw + 31) & 31;
                    const float v = su[cl * 320 + ((rs << 5) | ww)];
                    const int wb = ((c0 + cl) * 9 + kh * 3 + kw) * 8;
                    const float4 w0 = *(const float4*)&sw[wb];
                    const float4 w1 = *(const float4*)&sw[wb + 4];
                    acc[0] = fmaf(v, w0.x, acc[0]);
                    acc[1] = fmaf(v, w0.y, acc[1]);
                    acc[2] = fmaf(v, w0.z, acc[2]);
                    acc[3] = fmaf(v, w0.w, acc[3]);
                    acc[4] = fmaf(v, w1.x, acc[4]);
                    acc[5] = fmaf(v, w1.y, acc[5]);
                    acc[6] = fmaf(v, w1.z, acc[6]);
                    acc[7] = fmaf(v, w1.w, acc[7]);
                }
            }
        }
    }

    if (mode == 0) {
        const float dt = dtp[0];
        #pragma unroll
        for (int j = 0; j < 8; ++j) {
            const float x  = acc[j] + bd[cbase + j] + dt;
            const float sp = fmaxf(x, 0.f) + log1pf(expf(-fabsf(x)));
            ws[WS_DELTA + ((size_t)b * DM + cbase + j) * HW_ + pix] = sp;
        }
    } else if (mode == 1) {
        #pragma unroll
        for (int j = 0; j < 8; ++j)
            ws[WS_BV + ((size_t)b * DS + cbase + j) * HW_ + pix] = acc[j];
    } else {
        #pragma unroll
        for (int j = 0; j < 8; ++j)
            ws[WS_CV + ((size_t)b * DS + cbase + j) * HW_ + pix] = acc[j];
    }
}

// ---------------------------------------------------------------------------
// Kernel 2 (v10): R6's v5 structure with NT stores RESTORED (R10 A/B proved
// they're worth ~24 us: bypassing L2/MALL preserves s_prev MALL residency),
// plus: per-thread A/invA in registers (4 wave-uniform scalar loads + 4 expf)
// instead of the LDS table -- deletes the block-entry __syncthreads().
// 512 threads = 128 pixel-quads x 4 n-threads; grid B*NV*DM*2 = 4608 blocks.
// ---------------------------------------------------------------------------
__global__ __launch_bounds__(512) void scan_kernel(
    const float* __restrict__ u,
    const float* __restrict__ s_prev,
    const float* __restrict__ logA,
    const float* __restrict__ Dv,
    const float* __restrict__ ws,
    float* __restrict__ out)
{
    const int bid  = blockIdx.x >> 1;   // (b*9+v)*64 + c
    const int half = blockIdx.x & 1;
    const int c   = bid & 63;
    const int bv  = bid >> 6;
    const int v   = bv % 9;
    const int b   = bv / 9;

    __shared__ float syl[4 * 512];      // [nthr][quad*4+j]

    const int tid  = threadIdx.x;
    const int quad = tid & 127;
    const int nthr = tid >> 7;          // 0..3, wave-uniform
    const int lane = tid & 63;
    const int nb   = nthr << 2;

    // per-thread A / 1/A (wave-uniform n range -> scalar loads, no LDS/barrier)
    float Ar[4], Ir[4];
    #pragma unroll
    for (int i = 0; i < 4; ++i) {
        const float A = -__expf(logA[(c << 4) + nb + i]);
        Ar[i] = A;
        Ir[i] = 1.0f / A;
    }

    const int hw4 = (half << 9) | (quad << 2);   // first of 4 pixels
    const int h   = hw4 >> 5;

    const int sx  = v / 3 - 1;          // SHIFTS order: x outer, y inner
    const int syy = v % 3 - 1;
    const int hs  = (h + syy) & 31;
    const int rowbase = (hs << 5) | ((quad & 7) << 2);

    const int srcp = (lane & ~7) | ((lane + 1) & 7);  // next lane in row
    const int srcm = (lane & ~7) | ((lane + 7) & 7);  // prev lane in row

    const int bc = (b << 6) | c;

    const float* __restrict__ sp  = s_prev + ((size_t)bid << 14);
    float* __restrict__ so        = out + Y_SIZE + ((size_t)bid << 14);
    const float* __restrict__ bvp = ws + WS_BV + ((b << 14) | hw4);
    const float* __restrict__ cvp = ws + WS_CV + ((b << 14) | hw4);

    // s_prev first (HBM latency), then L2-resident operands
    float4 spv[4], bvv[4], cvv[4];
    #pragma unroll
    for (int i = 0; i < 4; ++i)
        spv[i] = *(const float4*)&sp[((nb + i) << 10) + rowbase];
    #pragma unroll
    for (int i = 0; i < 4; ++i) {
        bvv[i] = *(const float4*)&bvp[(nb + i) << 10];
        cvv[i] = *(const float4*)&cvp[(nb + i) << 10];
    }
    const float4 u4 = *(const float4*)&u[(bc << 10) | hw4];
    const float4 d4 = *(const float4*)&ws[WS_DELTA + ((bc << 10) | hw4)];

    float4 acc = make_float4(0.f, 0.f, 0.f, 0.f);
    #pragma unroll
    for (int i = 0; i < 4; ++i) {
        const int n = nb + i;
        float4 sh;
        if (sx > 0) {
            const float edge = __shfl(spv[i].x, srcp);
            sh = make_float4(spv[i].y, spv[i].z, spv[i].w, edge);
        } else if (sx < 0) {
            const float edge = __shfl(spv[i].w, srcm);
            sh = make_float4(edge, spv[i].x, spv[i].y, spv[i].z);
        } else {
            sh = spv[i];
        }
        const float A  = Ar[i];
        const float iA = Ir[i];
        float4 e;
        f32x4 s;
        e.x = __expf(d4.x * A);
        e.y = __expf(d4.y * A);
        e.z = __expf(d4.z * A);
        e.w = __expf(d4.w * A);
        s.x = fmaf(e.x, sh.x, (e.x - 1.f) * iA * bvv[i].x * u4.x);
        s.y = fmaf(e.y, sh.y, (e.y - 1.f) * iA * bvv[i].y * u4.y);
        s.z = fmaf(e.z, sh.z, (e.z - 1.f) * iA * bvv[i].z * u4.z);
        s.w = fmaf(e.w, sh.w, (e.w - 1.f) * iA * bvv[i].w * u4.w);
        __builtin_nontemporal_store(s, (f32x4*)&so[(n << 10) + hw4]);
        acc.x = fmaf(s.x, cvv[i].x, acc.x);
        acc.y = fmaf(s.y, cvv[i].y, acc.y);
        acc.z = fmaf(s.z, cvv[i].z, acc.z);
        acc.w = fmaf(s.w, cvv[i].w, acc.w);
    }

    // reduce y over the 4 n-threads
    *(float4*)&syl[(nthr << 9) | (quad << 2)] = make_float4(acc.x, acc.y, acc.z, acc.w);
    __syncthreads();
    if (tid < 128) {
        const float4 a0 = *(const float4*)&syl[(0 << 9) | (tid << 2)];
        const float4 a1 = *(const float4*)&syl[(1 << 9) | (tid << 2)];
        const float4 a2 = *(const float4*)&syl[(2 << 9) | (tid << 2)];
        const float4 a3 = *(const float4*)&syl[(3 << 9) | (tid << 2)];
        const float Dc = Dv[c];
        f32x4 y;
        y.x = a0.x + a1.x + a2.x + a3.x + u4.x * Dc;
        y.y = a0.y + a1.y + a2.y + a3.y + u4.y * Dc;
        y.z = a0.z + a1.z + a2.z + a3.z + u4.z * Dc;
        y.w = a0.w + a1.w + a2.w + a3.w + u4.w * Dc;
        __builtin_nontemporal_store(y, (f32x4*)&out[(bid << 10) | hw4]);
    }
}

extern "C" void kernel_launch(void* const* d_in, const int* in_sizes, int n_in,
                              void* d_out, int out_size, void* d_ws, size_t ws_size,
                              hipStream_t stream) {
    const float* u      = (const float*)d_in[0];
    const float* s_prev = (const float*)d_in[1];
    const float* Wd     = (const float*)d_in[2];
    const float* bd     = (const float*)d_in[3];
    const float* Wb     = (const float*)d_in[4];
    const float* Wc     = (const float*)d_in[5];
    const float* logA   = (const float*)d_in[6];
    const float* Dv     = (const float*)d_in[7];
    const float* dtp    = (const float*)d_in[8];
    float* out = (float*)d_out;
    float* ws  = (float*)d_ws;

    conv_kernel<<<B_ * 12 * 4, 256, 0, stream>>>(u, Wd, bd, Wb, Wc, dtp, ws);
    scan_kernel<<<B_ * NV * DM * 2, 512, 0, stream>>>(u, s_prev, logA, Dv, ws, out);
}